// Round 7
// baseline (271.107 us; speedup 1.0000x reference)
//
#include <hip/hip_runtime.h>
#include <hip/hip_fp16.h>

typedef _Float16 half_t;
typedef __attribute__((ext_vector_type(8))) _Float16 half8;
typedef __attribute__((ext_vector_type(4))) float floatx4;

// async global->LDS, 16B/lane. LDS base must be wave-uniform; HW adds lane*16.
__device__ __forceinline__ void async_copy16(const void* src, void* dst_lds) {
  __builtin_amdgcn_global_load_lds(
      (__attribute__((address_space(1))) void*)src,
      (__attribute__((address_space(3))) void*)dst_lds, 16, 0, 0);
}

// ---------------------------------------------------------------------------
// NT GEMM: C[M x N] = A[M x K] * B[N x K]^T, fp16 in, fp32 accum
// (mfma 16x16x32). BM=128, BN in {64,128}. 256 thr = 4 waves (2x2).
// BK=64, XOR-swizzled LDS (chunk = logical ^ (row&7)): 0 bank conflicts.
// EPI: 0 = fp16 store*scale, 2 = f32 store*scale,
//      5 = quantum fp16 store: (fp16)(qab[2c]*cos(v)+qab[2c+1]*sin(v)),
//      6 = y/V4 split: col<1024 -> y[row*1024+col] fp16;
//          1024<=col<1088 -> V4th[(col-1024)*8192+row] fp16; else discard.
// z: z2 = z>>zShift, z1 = z & mask; offsets z1*s?z1 + z2*s?z2 (elements).
template<int BN, int EPI>
__global__ __launch_bounds__(256) void gemm_nt(
    const half_t* __restrict__ A, const half_t* __restrict__ B,
    void* __restrict__ Cout,
    int lda, int ldb, int ldc, int kIters, int zShift,
    long sAz1, long sBz1, long sCz1,
    long sAz2, long sBz2, long sCz2, float scale,
    const void* __restrict__ aux)
{
  constexpr int BM = 128;
  constexpr int WN = BN / 2;          // wave tile N (64 or 32)
  constexpr int AN = WN / 16;         // acc blocks in N (4 or 2)
  constexpr int RA = BM * 8 / 256;    // A 16B-chunks per thread (4)
  constexpr int RB = BN * 8 / 256;    // B chunks per thread (4 or 2)
  __shared__ __align__(16) half_t lA[BM * 64];
  __shared__ __align__(16) half_t lB[BN * 64];

  const int tid  = threadIdx.x;
  const int wave = tid >> 6, lane = tid & 63;
  const int wm = wave >> 1, wn = wave & 1;
  const int er = lane >> 4, ec = lane & 15;   // k-quad / row-in-16
  const int sw = ec & 7;                      // read-side swizzle (row&7)

  const long z = blockIdx.z;
  const long z2 = z >> zShift;
  const long z1 = z - (z2 << zShift);
  const half_t* Ab = A + (long)blockIdx.x * BM * lda + z1 * sAz1 + z2 * sAz2;
  const half_t* Bb = B + (long)blockIdx.y * BN * ldb + z1 * sBz1 + z2 * sBz2;
  const long cz = z1 * sCz1 + z2 * sCz2;

  floatx4 acc[4][AN];
  #pragma unroll
  for (int i = 0; i < 4; i++)
    #pragma unroll
    for (int j = 0; j < AN; j++)
      acc[i][j] = (floatx4){0.f, 0.f, 0.f, 0.f};

  for (int ks = 0; ks < kIters; ++ks) {
    const half_t* Ak = Ab + ks * 64;
    const half_t* Bk = Bb + ks * 64;
    #pragma unroll
    for (int r = 0; r < RA; r++) {
      int s = r * 256 + tid;                  // LDS 16B slot
      int row = s >> 3;
      int kq = (s & 7) ^ (row & 7);           // swizzled source chunk
      async_copy16(Ak + (long)row * lda + kq * 8,
                   &lA[(r * 256 + wave * 64) * 8]);
    }
    #pragma unroll
    for (int r = 0; r < RB; r++) {
      int s = r * 256 + tid;
      int row = s >> 3;
      int kq = (s & 7) ^ (row & 7);
      async_copy16(Bk + (long)row * ldb + kq * 8,
                   &lB[(r * 256 + wave * 64) * 8]);
    }
    __syncthreads();   // drains vmcnt: LDS staged

    #pragma unroll
    for (int h = 0; h < 2; h++) {             // two 32-k sub-steps
      half8 af[4], bfv[AN];
      #pragma unroll
      for (int i = 0; i < 4; i++) {
        int row = wm * 64 + i * 16 + ec;
        af[i] = *(const half8*)&lA[row * 64 + (((h * 4 + er) ^ sw) * 8)];
      }
      #pragma unroll
      for (int j = 0; j < AN; j++) {
        int row = wn * WN + j * 16 + ec;
        bfv[j] = *(const half8*)&lB[row * 64 + (((h * 4 + er) ^ sw) * 8)];
      }
      #pragma unroll
      for (int i = 0; i < 4; i++)
        #pragma unroll
        for (int j = 0; j < AN; j++)
          acc[i][j] = __builtin_amdgcn_mfma_f32_16x16x32_f16(
              af[i], bfv[j], acc[i][j], 0, 0, 0);
    }
    __syncthreads();   // WAR before next stage
  }

  const long rowBase = (long)blockIdx.x * BM + wm * 64;
  const long colBase = (long)blockIdx.y * BN + wn * WN;
  #pragma unroll
  for (int i = 0; i < 4; i++)
    #pragma unroll
    for (int j = 0; j < AN; j++)
      #pragma unroll
      for (int r = 0; r < 4; r++) {
        long row = rowBase + i * 16 + er * 4 + r;   // C/D: row = quad*4+reg
        long col = colBase + j * 16 + ec;           // C/D: col = lane&15
        float v = acc[i][j][r];
        if constexpr (EPI == 0) {
          ((half_t*)Cout)[cz + row * (long)ldc + col] = (_Float16)(v * scale);
        } else if constexpr (EPI == 2) {
          ((float*)Cout)[cz + row * (long)ldc + col] = v * scale;
        } else if constexpr (EPI == 5) {
          const float* qab = (const float*)aux;
          float za = qab[2 * (int)col], zb = qab[2 * (int)col + 1];
          float zv = za * cosf(v) + zb * sinf(v);
          ((half_t*)Cout)[cz + row * (long)ldc + col] = (_Float16)zv;
        } else {   // EPI == 6: y columns + transposed V4 columns
          if (col < 1024) {
            ((half_t*)Cout)[row * 1024 + col] = (_Float16)v;
          } else if (col < 1088) {
            ((half_t*)aux)[(col - 1024) * 8192 + row] = (_Float16)v;
          }
        }
      }
}

// ---------------------------------------------------------------------------
// In-place row softmax over 2048 fp16 (row stride ld halves).
__global__ __launch_bounds__(256) void softmax_rows(half_t* __restrict__ S,
                                                    int ld)
{
  const long row = blockIdx.x;
  half8* sp = (half8*)(S + row * (long)ld);
  const int t = threadIdx.x;
  const int wave = t >> 6, lane = t & 63;
  half8 hv = sp[t];
  float e[8];
  #pragma unroll
  for (int k = 0; k < 8; k++) e[k] = (float)hv[k];
  float m = e[0];
  #pragma unroll
  for (int k = 1; k < 8; k++) m = fmaxf(m, e[k]);
  #pragma unroll
  for (int o = 32; o > 0; o >>= 1) m = fmaxf(m, __shfl_xor(m, o));
  __shared__ float rmax[4], rsum[4];
  if (lane == 0) rmax[wave] = m;
  __syncthreads();
  m = fmaxf(fmaxf(rmax[0], rmax[1]), fmaxf(rmax[2], rmax[3]));
  float s = 0.f;
  #pragma unroll
  for (int k = 0; k < 8; k++) { e[k] = expf(e[k] - m); s += e[k]; }
  #pragma unroll
  for (int o = 32; o > 0; o >>= 1) s += __shfl_xor(s, o);
  if (lane == 0) rsum[wave] = s;
  __syncthreads();
  float inv = 1.f / (rsum[0] + rsum[1] + rsum[2] + rsum[3]);
  half8 o8;
  #pragma unroll
  for (int k = 0; k < 8; k++) o8[k] = (_Float16)(e[k] * inv);
  sp[t] = o8;
}

// ---------------------------------------------------------------------------
// ONE prep kernel (grid-partitioned):
//  [0,4096)      : cvt x fp32 -> fp16
//  [4096,4608)   : WqT[c][r] = Wq[r][c] fp16 (coalesced read, scattered write)
//  [4608,5120)   : WkT[c][r] = Wk[r][c] fp16
//  [5120,5152)   : Wcat rows 1024..1087 = gathered Wv rows (fp16)
//  [5152,5184)   : Wcat rows 1088..1151 = 0 (pad)
//  [5184,5440)   : Wos[e][c] = Wo[e][gather(c)] fp16
//  5440          : quantum circuit constants (A=<Z_q>, B=-<X_q> per head)
__global__ __launch_bounds__(256) void prep_all(
    const float* __restrict__ x,  const float* __restrict__ Wq,
    const float* __restrict__ Wk, const float* __restrict__ Wv,
    const float* __restrict__ Wo, const float* __restrict__ qp, int L,
    half_t* __restrict__ xh, half_t* __restrict__ WqT,
    half_t* __restrict__ WkT, half_t* __restrict__ Wcat,
    half_t* __restrict__ Wos, float* __restrict__ qab)
{
  const int bid = blockIdx.x;
  if (bid < 4096) {                      // x -> fp16
    long i = ((long)bid * 256 + threadIdx.x) * 8;
    float4 a = *(const float4*)(x + i);
    float4 b = *(const float4*)(x + i + 4);
    half8 h = {(_Float16)a.x, (_Float16)a.y, (_Float16)a.z, (_Float16)a.w,
               (_Float16)b.x, (_Float16)b.y, (_Float16)b.z, (_Float16)b.w};
    *(half8*)(xh + i) = h;
  } else if (bid < 5120) {               // Wq / Wk transpose -> fp16
    const int base = bid < 4608 ? 4096 : 4608;
    const float* src = bid < 4608 ? Wq : Wk;
    half_t* dst = bid < 4608 ? WqT : WkT;
    long i = ((long)(bid - base) * 256 + threadIdx.x) * 8;   // over 1024*1024
    int r = (int)(i >> 10), c = (int)(i & 1023);
    float4 a = *(const float4*)(src + (long)r * 1024 + c);
    float4 b = *(const float4*)(src + (long)r * 1024 + c + 4);
    float vv[8] = {a.x, a.y, a.z, a.w, b.x, b.y, b.z, b.w};
    #pragma unroll
    for (int j = 0; j < 8; j++)
      dst[(long)(c + j) * 1024 + r] = (_Float16)vv[j];
  } else if (bid < 5152) {               // Wv gather -> Wcat rows 1024..1087
    long i = ((long)(bid - 5120) * 256 + threadIdx.x) * 8;   // over 64*1024
    int c = (int)(i >> 10);
    int e = (int)(i & 1023);
    const float* src = Wv + (long)(((c >> 2) << 6) | (c & 3)) * 1024 + e;
    float4 a = *(const float4*)src;
    float4 b = *(const float4*)(src + 4);
    half8 h = {(_Float16)a.x, (_Float16)a.y, (_Float16)a.z, (_Float16)a.w,
               (_Float16)b.x, (_Float16)b.y, (_Float16)b.z, (_Float16)b.w};
    *(half8*)(Wcat + (long)1024 * 1024 + i) = h;
  } else if (bid < 5184) {               // Wcat pad rows 1088..1151 = 0
    long i = ((long)(bid - 5152) * 256 + threadIdx.x) * 8;
    *(half8*)(Wcat + (long)1088 * 1024 + i) = (half8){0,0,0,0,0,0,0,0};
  } else if (bid < 5440) {               // Wos pack
    int idx = (bid - 5184) * 256 + threadIdx.x;   // 1024*64
    int e = idx >> 6, c = idx & 63;
    Wos[idx] = (_Float16)Wo[(long)e * 1024 + (((c >> 2) << 6) | (c & 3))];
  } else {                               // quantum circuit constants
    int h = threadIdx.x;
    if (h >= 16) return;
    float st[16];
    #pragma unroll
    for (int i = 0; i < 16; i++) st[i] = 0.f;
    st[0] = 1.f;
    for (int l = 0; l < L; l++) {
      #pragma unroll
      for (int q = 0; q < 4; q++) {
        float th = qp[(h * L + l) * 4 + q];
        float c = cosf(0.5f * th), s = sinf(0.5f * th);
        int mq = 8 >> q;
        #pragma unroll
        for (int i = 0; i < 16; i++) {
          if ((i & mq) == 0) {
            float a0 = st[i], a1 = st[i | mq];
            st[i]      = c * a0 - s * a1;
            st[i | mq] = s * a0 + c * a1;
          }
        }
      }
      const int cm[4] = {8, 4, 2, 1};   // CNOT (0,1)(1,2)(2,3)(3,0)
      const int tm[4] = {4, 2, 1, 8};
      #pragma unroll
      for (int p = 0; p < 4; p++) {
        int mc = cm[p], mt = tm[p];
        #pragma unroll
        for (int i = 0; i < 16; i++) {
          if ((i & mc) != 0 && (i & mt) == 0) {
            float tv = st[i]; st[i] = st[i | mt]; st[i | mt] = tv;
          }
        }
      }
    }
    #pragma unroll
    for (int q = 0; q < 4; q++) {
      int mq = 8 >> q;
      float zc = 0.f, xc = 0.f;
      #pragma unroll
      for (int i = 0; i < 16; i++) {
        float p2 = st[i] * st[i];
        zc += ((i & mq) == 0) ? p2 : -p2;
        if ((i & mq) == 0) xc += st[i] * st[i | mq];
      }
      qab[(h * 4 + q) * 2 + 0] = zc;
      qab[(h * 4 + q) * 2 + 1] = -2.f * xc;
    }
  }
}

// ---------------------------------------------------------------------------
extern "C" void kernel_launch(void* const* d_in, const int* in_sizes, int n_in,
                              void* d_out, int out_size, void* d_ws, size_t ws_size,
                              hipStream_t stream)
{
  const float* x  = (const float*)d_in[0];
  const float* Wq = (const float*)d_in[1];
  const float* Wk = (const float*)d_in[2];
  const float* Wv = (const float*)d_in[3];
  const float* Wo = (const float*)d_in[4];
  const float* qp = (const float*)d_in[5];
  const int L = in_sizes[5] / 64;     // H*NQ = 64
  float* out = (float*)d_out;

  // B=4, T=2048, E=1024, H=16, hd=64, NQ=4; 8192 tokens.
  char* w = (char*)d_ws;
  size_t off = 0;
  auto alloc = [&](size_t bytes) -> void* {
    void* p = w + off;
    off = (off + bytes + 255) & ~(size_t)255;
    return p;
  };
  float*  qab  = (float*)alloc(512);
  half_t* xh   = (half_t*)alloc((size_t)8192 * 1024 * 2);
  half_t* WqT  = (half_t*)alloc((size_t)1024 * 1024 * 2);
  half_t* WkT  = (half_t*)alloc((size_t)1024 * 1024 * 2);
  half_t* Wcat = (half_t*)alloc((size_t)1152 * 1024 * 2);  // [Wt; Wv4; pad]
  half_t* Wos  = (half_t*)alloc((size_t)1024 * 64 * 2);
  half_t* V4th = (half_t*)alloc((size_t)64 * 8192 * 2);    // [chan][token]
  half_t* y    = (half_t*)alloc((size_t)8192 * 1024 * 2);
  half_t* Z4   = (half_t*)alloc((size_t)8192 * 64 * 2);
  // total ~42.3 MB (tier-0 ws >= ~57 MB confirmed by prior rounds).

  // S (fp16 scores/probs, in-place softmax) lives in d_out: 8192*2048*2 B
  // = 33.55 MB = d_out exactly; fully consumed by PV before final GEMM
  // overwrites d_out (stream-ordered).
  half_t* S = (half_t*)d_out;

  // --- 1 prep dispatch ---
  prep_all<<<dim3(5441), dim3(256), 0, stream>>>(
      x, Wq, Wk, Wv, Wo, qp, L, xh, WqT, WkT, Wcat, Wos, qab);

  // --- Wt[f,e] = sum_g Wk[g,f] Wq[g,e]  (1024x1024, K=1024) -> Wcat rows 0..1023
  gemm_nt<64, 0><<<dim3(8, 16, 1), 256, 0, stream>>>(
      WkT, WqT, Wcat, 1024, 1024, 1024, 16, 0,
      0, 0, 0, 0, 0, 0, 1.f, nullptr);

  // --- y = xh @ Wcat^T (8192 x 1152, K=1024): cols 0..1023 -> y,
  //     cols 1024..1087 -> V4th transposed, cols 1088+ discarded.
  gemm_nt<128, 6><<<dim3(64, 9, 1), 256, 0, stream>>>(
      xh, Wcat, y, 1024, 1024, 1024, 16, 0,
      0, 0, 0, 0, 0, 0, 1.f, V4th);

  // --- scores_b = (y_b @ xh_b^T) / 32 -> fp16 S, z = batch ---
  gemm_nt<128, 0><<<dim3(16, 16, 4), 256, 0, stream>>>(
      y, xh, S, 1024, 1024, 2048, 16, 0,
      0, 0, 0, (long)2048 * 1024, (long)2048 * 1024, (long)2048 * 2048,
      0.03125f, nullptr);

  softmax_rows<<<dim3(8192), dim3(256), 0, stream>>>(S, 2048);

  // --- PV + quantum epilogue -> Z4 fp16: z = batch, K=2048 ---
  gemm_nt<64, 5><<<dim3(16, 1, 4), 256, 0, stream>>>(
      S, V4th, Z4, 2048, 8192, 64, 32, 0,
      0, 0, 0, (long)2048 * 2048, 2048, (long)2048 * 64, 1.f, qab);

  // --- final: out = Z4 @ Wos^T  (8192 x 1024, K=64, fp32 store) ---
  gemm_nt<128, 2><<<dim3(64, 8, 1), 256, 0, stream>>>(
      Z4, Wos, out, 64, 64, 1024, 1, 0, 0, 0, 0, 0, 0, 0, 1.f, nullptr);
}